// Round 7
// baseline (182.648 us; speedup 1.0000x reference)
//
#include <hip/hip_runtime.h>

#define BATCH 4
#define CCH 128
#define NSP 4096
#define NGRP 8
#define GROUP_ELEMS 65536   // 16 ch * 4096
// ATT_SCALE * log2(e): folded into q at qkv_gemm so softmax is exp2(s)
#define QSCALE 0.12751744f
#define EPS_GN 1e-5f
#define OPSTRIDE 2097152    // 4*4096*128 shorts per kh partial
#define LPSTRIDE 16384      // 4*4096 floats per kh partial

typedef short s8b __attribute__((ext_vector_type(8)));
typedef float f32x4 __attribute__((ext_vector_type(4)));

static __device__ __forceinline__ short f2bf(float f) {
  union { float f; unsigned u; } v; v.f = f;
  unsigned r = (v.u + 0x7FFFu + ((v.u >> 16) & 1u)) >> 16;
  return (short)r;
}

static __device__ __forceinline__ float bf2f(short s) {
  unsigned u = ((unsigned)(unsigned short)s) << 16;
  float f; __builtin_memcpy(&f, &u, 4); return f;
}

static __device__ __forceinline__ float fexp2(float x) {
#if __has_builtin(__builtin_amdgcn_exp2f)
  return __builtin_amdgcn_exp2f(x);
#else
  return exp2f(x);
#endif
}

// pack two floats to adjacent bf16 (round-half-up) in one u32: lo=a, hi=b
static __device__ __forceinline__ unsigned pack2bf(float a, float b) {
  unsigned ua, ub;
  __builtin_memcpy(&ua, &a, 4); __builtin_memcpy(&ub, &b, 4);
  ua += 0x8000u; ub += 0x8000u;
#if __has_builtin(__builtin_amdgcn_perm)
  return __builtin_amdgcn_perm(ub, ua, 0x07060302u);  // bytes: ua[3:2] | ub[3:2]
#else
  return (ua >> 16) | (ub & 0xFFFF0000u);
#endif
}

static __device__ __forceinline__ f32x4 mfma16(s8b a, s8b b, f32x4 c) {
  return __builtin_amdgcn_mfma_f32_16x16x32_bf16(a, b, c, 0, 0, 0);
}

// async 16B global->LDS DMA; dest = wave-uniform base + lane*16
static __device__ __forceinline__ void async16(const void* g, void* l) {
  __builtin_amdgcn_global_load_lds(
      (const __attribute__((address_space(1))) void*)g,
      (__attribute__((address_space(3))) void*)l, 16, 0, 0);
}

// ---------------- GroupNorm pass 1: per-(b,g,chunk) partial sum/sumsq ----------------
__global__ void gn_stats(const float* __restrict__ x, float* __restrict__ part) {
  int bx = blockIdx.x;            // 256 = bg(32) * chunk(8)
  int ch = bx & 7, bg = bx >> 3;
  const float* base = x + (size_t)bg * GROUP_ELEMS + (size_t)ch * 8192;
  int t = threadIdx.x;
  float s = 0.f, ss = 0.f;
  #pragma unroll
  for (int i = 0; i < 8; ++i) {
    float4 v = *(const float4*)(base + i * 1024 + t * 4);
    s  += v.x + v.y + v.z + v.w;
    ss += v.x * v.x + v.y * v.y + v.z * v.z + v.w * v.w;
  }
  #pragma unroll
  for (int off = 1; off < 64; off <<= 1) {
    s  += __shfl_xor(s, off);
    ss += __shfl_xor(ss, off);
  }
  __shared__ float red[8];
  int w = t >> 6;
  if ((t & 63) == 0) { red[w * 2] = s; red[w * 2 + 1] = ss; }
  __syncthreads();
  if (t == 0) {
    part[bx * 2]     = red[0] + red[2] + red[4] + red[6];
    part[bx * 2 + 1] = red[1] + red[3] + red[5] + red[7];
  }
}

// ---------------- GroupNorm pass 2: reduce partials, normalize, write xn (b,n,c) bf16 ----------------
__global__ void gn_apply(const float* __restrict__ x, const float* __restrict__ gw,
                         const float* __restrict__ gb, const float* __restrict__ part,
                         short* __restrict__ xn) {
  int bx = blockIdx.x;            // 256 = b(4) g(8) ns(8)
  int ns = bx & 7, g = (bx >> 3) & 7, b = bx >> 6;
  int bg = b * NGRP + g;
  float s = 0.f, ss = 0.f;
  #pragma unroll
  for (int j = 0; j < 8; ++j) {
    s  += part[(bg * 8 + j) * 2];
    ss += part[(bg * 8 + j) * 2 + 1];
  }
  float mean = s * (1.f / GROUP_ELEMS);
  float var  = ss * (1.f / GROUP_ELEMS) - mean * mean;
  float inv  = rsqrtf(var + EPS_GN);
  int t = threadIdx.x;
  int cl = t & 15, n4 = t >> 4;
  int c = g * 16 + cl;
  float ga = gw[c] * inv;
  float be = gb[c] - mean * ga;
  const float* xr = x + (size_t)(b * CCH + c) * NSP;
  short* xo = xn + (size_t)b * NSP * CCH + c;
  #pragma unroll
  for (int i = 0; i < 8; ++i) {
    int n = ns * 512 + i * 64 + n4 * 4;
    float4 v = *(const float4*)(xr + n);
    xo[(size_t)(n + 0) * CCH] = f2bf(v.x * ga + be);
    xo[(size_t)(n + 1) * CCH] = f2bf(v.y * ga + be);
    xo[(size_t)(n + 2) * CCH] = f2bf(v.z * ga + be);
    xo[(size_t)(n + 3) * CCH] = f2bf(v.w * ga + be);
  }
}

// ---------------- Fused QKV: bx<1024 -> q,k (D[n][o]); else -> v (D[o][n], permuted key order) ----------------
// v is written TRANSPOSED (b,c,n) with each 64-key group's key order permuted:
// orig key o = g2*16+l15  ->  pos = l15*2 + (g2&1) + 32*(g2>>1)
// so flash's P-pack can emit LDS-adjacent bf16 pairs. PV is key-order invariant.
__global__ void qkv_gemm(const short* __restrict__ xn, const float* __restrict__ Wqkv,
                         const float* __restrict__ bias, short* __restrict__ q,
                         short* __restrict__ k, short* __restrict__ vt) {
  __shared__ short Xl[128 * 136];
  __shared__ short Wl[64 * 136];
  int bx = blockIdx.x;
  int t = threadIdx.x;
  int lane = t & 63, w = t >> 6, l15 = lane & 15, quad = lane >> 4;
  if (bx < 1024) {
    // ---------- q,k part ----------
    int ot = bx & 3, nt = (bx >> 2) & 63, b = bx >> 8;
    for (int idx = t; idx < 64 * 16; idx += 256) {
      int row = idx >> 4, c8 = idx & 15;
      *(s8b*)&Xl[row * 136 + c8 * 8] =
          *(const s8b*)(xn + ((size_t)(b * NSP + nt * 64 + row)) * CCH + c8 * 8);
    }
    for (int idx = t; idx < 64 * 16; idx += 256) {
      int row = idx >> 4, c8 = idx & 15;
      const float* src = Wqkv + (size_t)(ot * 64 + row) * CCH + c8 * 8;
      s8b wv;
      #pragma unroll
      for (int j = 0; j < 8; ++j) wv[j] = f2bf(src[j]);
      *(s8b*)&Wl[row * 136 + c8 * 8] = wv;
    }
    __syncthreads();
    s8b a[4];
    #pragma unroll
    for (int kc = 0; kc < 4; ++kc)
      a[kc] = *(const s8b*)&Xl[(w * 16 + l15) * 136 + kc * 32 + quad * 8];
    #pragma unroll
    for (int o4 = 0; o4 < 4; ++o4) {
      f32x4 acc = {0.f, 0.f, 0.f, 0.f};
      #pragma unroll
      for (int kc = 0; kc < 4; ++kc) {
        s8b bw = *(const s8b*)&Wl[(o4 * 16 + l15) * 136 + kc * 32 + quad * 8];
        acc = mfma16(a[kc], bw, acc);
      }
      int obase = ot * 64 + o4 * 16;
      short* dst = (obase < 128) ? q : k;
      float mulf = (obase < 128) ? QSCALE : 1.0f;
      int oc = obase - ((obase < 128) ? 0 : 128) + l15;
      float bs = bias[obase + l15];
      #pragma unroll
      for (int r = 0; r < 4; ++r) {
        int n = nt * 64 + w * 16 + quad * 4 + r;
        dst[((size_t)(b * NSP + n)) * CCH + oc] = f2bf((acc[r] + bs) * mulf);
      }
    }
  } else {
    // ---------- v part ----------
    int vbx = bx - 1024;            // 256 = b(4) nt(32) ot(2)
    int ot = vbx & 1, nt = (vbx >> 1) & 31, b = vbx >> 6;
    for (int idx = t; idx < 128 * 16; idx += 256) {
      int row = idx >> 4, c8 = idx & 15;
      *(s8b*)&Xl[row * 136 + c8 * 8] =
          *(const s8b*)(xn + ((size_t)(b * NSP + nt * 128 + row)) * CCH + c8 * 8);
    }
    for (int idx = t; idx < 64 * 16; idx += 256) {
      int row = idx >> 4, c8 = idx & 15;
      const float* src = Wqkv + (size_t)(256 + ot * 64 + row) * CCH + c8 * 8;
      s8b wv;
      #pragma unroll
      for (int j = 0; j < 8; ++j) wv[j] = f2bf(src[j]);
      *(s8b*)&Wl[row * 136 + c8 * 8] = wv;
    }
    __syncthreads();
    s8b a[4];
    #pragma unroll
    for (int kc = 0; kc < 4; ++kc)
      a[kc] = *(const s8b*)&Wl[(w * 16 + l15) * 136 + kc * 32 + quad * 8];
    float bs[4];
    #pragma unroll
    for (int r = 0; r < 4; ++r) bs[r] = bias[256 + ot * 64 + w * 16 + quad * 4 + r];
    #pragma unroll
    for (int ntile = 0; ntile < 8; ++ntile) {
      f32x4 acc = {0.f, 0.f, 0.f, 0.f};
      #pragma unroll
      for (int kc = 0; kc < 4; ++kc) {
        s8b bx2 = *(const s8b*)&Xl[(ntile * 16 + l15) * 136 + kc * 32 + quad * 8];
        acc = mfma16(a[kc], bx2, acc);
      }
      int g2 = ntile & 3;
      int npos = nt * 128 + (ntile >> 2) * 64 + l15 * 2 + (g2 & 1) + 32 * (g2 >> 1);
      #pragma unroll
      for (int r = 0; r < 4; ++r) {
        int og = ot * 64 + w * 16 + quad * 4 + r;     // v channel
        vt[((size_t)(b * CCH + og)) * NSP + npos] = f2bf(acc[r] + bs[r]);
      }
    }
  }
}

// ---------------- Flash attention v7: 64 q-rows/wave, halved LDS-fragment traffic ----------------
// Grid 256 = qt(8: 512-row tiles) x b(4) x kh(8: 512-key eighths); 1 block/CU.
// Block 512 thr = 8 waves x 64 q-rows (mt=4). Q resident (64 VGPR), O[4][8] in
// AGPR (128). K/V tiles (64 keys) double-buffered via global_load_lds with XOR
// source swizzle. Full 64-row per-wave P buffer (Pl[8][64*72], LDS 136KB total)
// lets K B-frags be read ONCE per iter and shared across all 4 m-tiles -- this
// halves per-FLOP LDS traffic vs the mt=2 version (the measured bottleneck).
// Fixed-max softmax: p=exp2(s) (q pre-scaled), l via MFMA-with-ones; partial
// bf16 O + fp32 l per kh, merged inside proj_gemm.
__global__ __launch_bounds__(512) void flash(const short* __restrict__ q,
                                             const short* __restrict__ k,
                                             const short* __restrict__ vt,
                                             short* __restrict__ Op,
                                             float* __restrict__ Lp) {
  int bx = blockIdx.x;                // 256 = qt(8) b(4) kh(8)
  int kh = bx & 7, b = (bx >> 3) & 3, qt = bx >> 5;
  __shared__ short Kl[2][64 * 128];   // [key][ch], 8-short groups XOR-swizzled by (key&15)
  __shared__ short Vl[2][128 * 64];   // [ch][pos], 8-short groups XOR-swizzled by (ch&7)
  __shared__ short Pl[8][64 * 72];    // per-wave 64-row P transpose, pitch 72
  int t = threadIdx.x;
  int lane = t & 63, w = t >> 6;      // w in [0,8)
  int l15 = lane & 15, quad = lane >> 4;
  const short* kbase = k + (size_t)b * NSP * CCH;
  const short* vbase = vt + (size_t)b * CCH * NSP;
  int kt0 = kh * 512;

  int krow_in_chunk = lane >> 4, kgrp = lane & 15;
  int vrow_in_chunk = lane >> 3, vgrp = lane & 7;

  // Q A-fragments, resident: rows qt*512 + w*64 + mt*16 + l15
  s8b aq[4][4];
  #pragma unroll
  for (int mt = 0; mt < 4; ++mt) {
    const short* qp =
        q + ((size_t)(b * NSP + qt * 512 + w * 64 + mt * 16 + l15)) * CCH + quad * 8;
    #pragma unroll
    for (int kc = 0; kc < 4; ++kc) aq[mt][kc] = *(const s8b*)(qp + kc * 32);
  }
  f32x4 O[4][8];
  f32x4 L[4];
  #pragma unroll
  for (int mt = 0; mt < 4; ++mt) {
    #pragma unroll
    for (int cg = 0; cg < 8; ++cg) O[mt][cg] = (f32x4){0.f, 0.f, 0.f, 0.f};
    L[mt] = (f32x4){0.f, 0.f, 0.f, 0.f};
  }
  s8b vone;
  #pragma unroll
  for (int j = 0; j < 8; ++j) vone[j] = (short)0x3F80;   // bf16 1.0
  short* pw = &Pl[w][0];

  // stage one 64-key tile (K 16KB + V 16KB); 8 waves x 4 DMA instrs
  #define STAGE(buf_, key0_)                                                        \
    {                                                                               \
      const int key0v = (key0_);                                                    \
      _Pragma("unroll") for (int si = 0; si < 2; ++si) {                            \
        int c = w * 2 + si;                                                         \
        int rt = c * 4 + krow_in_chunk;                                             \
        async16(kbase + (size_t)(key0v + rt) * CCH + ((kgrp ^ (rt & 15)) * 8),      \
                &Kl[buf_][c * 512]);                                                \
        int rc = c * 8 + vrow_in_chunk;                                             \
        async16(vbase + (size_t)rc * NSP + key0v + ((vgrp ^ (rc & 7)) * 8),         \
                &Vl[buf_][c * 512]);                                                \
      }                                                                             \
    }

  STAGE(0, kt0)
  __syncthreads();

  for (int i = 0; i < 8; ++i) {
    int buf = i & 1;
    if (i < 7) STAGE(buf ^ 1, kt0 + (i + 1) * 64)

    // ---- QK + softmax, streamed by g2-pair; K frags read once, shared over 4 m-tiles ----
    #pragma unroll
    for (int p = 0; p < 2; ++p) {
      const short* kpa = &Kl[buf][((2 * p) * 16 + l15) * 128];
      const short* kpb = &Kl[buf][((2 * p + 1) * 16 + l15) * 128];
      s8b bka[4], bkb[4];
      #pragma unroll
      for (int kc = 0; kc < 4; ++kc) {
        bka[kc] = *(const s8b*)&kpa[((kc * 4 + quad) ^ l15) * 8];
        bkb[kc] = *(const s8b*)&kpb[((kc * 4 + quad) ^ l15) * 8];
      }
      #pragma unroll
      for (int mt = 0; mt < 4; ++mt) {
        f32x4 sa = {0.f, 0.f, 0.f, 0.f};
        f32x4 sb = {0.f, 0.f, 0.f, 0.f};
        #pragma unroll
        for (int kc = 0; kc < 4; ++kc) sa = mfma16(aq[mt][kc], bka[kc], sa);
        #pragma unroll
        for (int kc = 0; kc < 4; ++kc) sb = mfma16(aq[mt][kc], bkb[kc], sb);
        #pragma unroll
        for (int r = 0; r < 4; ++r) {
          float p0 = fexp2(sa[r]);
          float p1 = fexp2(sb[r]);
          *(unsigned*)&pw[(mt * 16 + quad * 4 + r) * 72 + p * 32 + l15 * 2] =
              pack2bf(p0, p1);
        }
      }
    }
    // ---- P A-fragments (per-wave LDS, no barrier) ----
    s8b pf[4][2];
    #pragma unroll
    for (int mt = 0; mt < 4; ++mt) {
      pf[mt][0] = *(const s8b*)&pw[(mt * 16 + l15) * 72 + quad * 8];
      pf[mt][1] = *(const s8b*)&pw[(mt * 16 + l15) * 72 + 32 + quad * 8];
    }
    #pragma unroll
    for (int mt = 0; mt < 4; ++mt) {
      L[mt] = mfma16(pf[mt][0], vone, L[mt]);
      L[mt] = mfma16(pf[mt][1], vone, L[mt]);
    }
    // ---- O += P V : V frags read once, shared over 4 m-tiles ----
    #pragma unroll
    for (int cg = 0; cg < 8; ++cg) {
      const short* vp = &Vl[buf][(cg * 16 + l15) * 64];
      s8b vf0 = *(const s8b*)&vp[((quad) ^ (l15 & 7)) * 8];
      s8b vf1 = *(const s8b*)&vp[((4 + quad) ^ (l15 & 7)) * 8];
      #pragma unroll
      for (int mt = 0; mt < 4; ++mt) {
        O[mt][cg] = mfma16(pf[mt][0], vf0, O[mt][cg]);
        O[mt][cg] = mfma16(pf[mt][1], vf1, O[mt][cg]);
      }
    }
    __syncthreads();
  }

  // ---- write bf16 partial O + fp32 partial l for this kh ----
  short* ob = Op + (size_t)kh * OPSTRIDE + ((size_t)(b * NSP + qt * 512)) * CCH;
  float* lp = Lp + kh * LPSTRIDE + b * NSP + qt * 512;
  #pragma unroll
  for (int mt = 0; mt < 4; ++mt) {
    #pragma unroll
    for (int r = 0; r < 4; ++r) {
      int n = w * 64 + mt * 16 + quad * 4 + r;
      if (l15 == 0) lp[n] = L[mt][r];
      #pragma unroll
      for (int cg = 0; cg < 8; ++cg)
        ob[(size_t)n * CCH + cg * 16 + l15] = f2bf(O[mt][cg][r]);
    }
  }
}

// ---------------- proj + bias + residual, merging the 8 kh partials ----------------
__global__ void proj_gemm(const short* __restrict__ Op, const float* __restrict__ Lp,
                          const float* __restrict__ Wp, const float* __restrict__ pbias,
                          const float* __restrict__ x, float* __restrict__ out) {
  int bx = blockIdx.x;            // 256 = b(4) nt(64)
  int nt = bx & 63, b = bx >> 6;
  __shared__ short Wl[128][136];
  int t = threadIdx.x;
  for (int idx = t; idx < 128 * 16; idx += 256) {
    int row = idx >> 4, c8 = idx & 15;
    const float* src = Wp + (size_t)row * CCH + c8 * 8;
    s8b wv;
    #pragma unroll
    for (int j = 0; j < 8; ++j) wv[j] = f2bf(src[j]);
    *(s8b*)&Wl[row][c8 * 8] = wv;
  }
  __syncthreads();
  int lane = t & 63, w = t >> 6, l15 = lane & 15, quad = lane >> 4;
  int row = nt * 64 + w * 16 + l15;             // this lane's ao row (m index)
  float lsum = 0.f;
  #pragma unroll
  for (int s = 0; s < 8; ++s) lsum += Lp[s * LPSTRIDE + b * NSP + row];
  float linv = 1.f / lsum;
  const short* ap = Op + ((size_t)(b * NSP + row)) * CCH + quad * 8;
  s8b bfr[4];
  #pragma unroll
  for (int kc = 0; kc < 4; ++kc) {
    float acc8[8];
    #pragma unroll
    for (int j = 0; j < 8; ++j) acc8[j] = 0.f;
    #pragma unroll
    for (int s = 0; s < 8; ++s) {
      s8b tv = *(const s8b*)(ap + (size_t)s * OPSTRIDE + kc * 32);
      #pragma unroll
      for (int j = 0; j < 8; ++j) acc8[j] += bf2f(tv[j]);
    }
    #pragma unroll
    for (int j = 0; j < 8; ++j) bfr[kc][j] = f2bf(acc8[j] * linv);
  }
  #pragma unroll
  for (int cg = 0; cg < 8; ++cg) {
    f32x4 acc = {0.f, 0.f, 0.f, 0.f};
    #pragma unroll
    for (int kc = 0; kc < 4; ++kc) {
      s8b aw = *(const s8b*)&Wl[cg * 16 + l15][kc * 32 + quad * 8];
      acc = mfma16(aw, bfr[kc], acc);
    }
    #pragma unroll
    for (int r = 0; r < 4; ++r) {
      int co = cg * 16 + quad * 4 + r;
      int n = nt * 64 + w * 16 + l15;
      size_t off = ((size_t)(b * CCH + co)) * NSP + n;
      out[off] = x[off] + acc[r] + pbias[co];
    }
  }
}

extern "C" void kernel_launch(void* const* d_in, const int* in_sizes, int n_in,
                              void* d_out, int out_size, void* d_ws, size_t ws_size,
                              hipStream_t stream) {
  (void)in_sizes; (void)n_in; (void)out_size; (void)ws_size;
  const float* x    = (const float*)d_in[0];
  const float* gw   = (const float*)d_in[1];
  const float* gb   = (const float*)d_in[2];
  const float* Wqkv = (const float*)d_in[3];
  const float* bqkv = (const float*)d_in[4];
  const float* Wp   = (const float*)d_in[5];
  const float* bp   = (const float*)d_in[6];
  float* out = (float*)d_out;
  char* ws = (char*)d_ws;
  float* part = (float*)ws;                             // 512 floats
  short* xn    = (short*)(ws + 4096);
  short* q     = (short*)(ws + 4096 + 1ull * 4194304);
  short* k     = (short*)(ws + 4096 + 2ull * 4194304);
  short* vt    = (short*)(ws + 4096 + 3ull * 4194304);
  short* Opart = (short*)(ws + 4096 + 4ull * 4194304);  // 8 x 4MB bf16 partial O
  float* Lpart = (float*)(ws + 4096 + 12ull * 4194304); // 8 x 64KB fp32 partial l

  gn_stats<<<256, 256, 0, stream>>>(x, part);
  gn_apply<<<256, 256, 0, stream>>>(x, gw, gb, part, xn);
  qkv_gemm<<<1280, 256, 0, stream>>>(xn, Wqkv, bqkv, q, k, vt);
  flash<<<256, 512, 0, stream>>>(q, k, vt, Opart, Lpart);
  proj_gemm<<<256, 256, 0, stream>>>(Opart, Lpart, Wp, bp, x, out);
}

// Round 8
// 134.490 us; speedup vs baseline: 1.3581x; 1.3581x over previous
//
#include <hip/hip_runtime.h>

#define BATCH 4
#define CCH 128
#define NSP 4096
#define NGRP 8
#define GROUP_ELEMS 65536   // 16 ch * 4096
// ATT_SCALE * log2(e): folded into q at qkv_gemm so softmax is exp2(s)
#define QSCALE 0.12751744f
#define EPS_GN 1e-5f
#define OPSTRIDE 2097152    // 4*4096*128 shorts per kh partial
#define LPSTRIDE 16384      // 4*4096 floats per kh partial

typedef short s8b __attribute__((ext_vector_type(8)));
typedef float f32x4 __attribute__((ext_vector_type(4)));
typedef float f32x16 __attribute__((ext_vector_type(16)));

static __device__ __forceinline__ short f2bf(float f) {
  union { float f; unsigned u; } v; v.f = f;
  unsigned r = (v.u + 0x7FFFu + ((v.u >> 16) & 1u)) >> 16;
  return (short)r;
}

static __device__ __forceinline__ float bf2f(short s) {
  unsigned u = ((unsigned)(unsigned short)s) << 16;
  float f; __builtin_memcpy(&f, &u, 4); return f;
}

static __device__ __forceinline__ float fexp2(float x) {
#if __has_builtin(__builtin_amdgcn_exp2f)
  return __builtin_amdgcn_exp2f(x);
#else
  return exp2f(x);
#endif
}

// pack two floats to adjacent bf16 (round-half-up) in one u32: lo=a, hi=b
static __device__ __forceinline__ unsigned pack2bf(float a, float b) {
  unsigned ua, ub;
  __builtin_memcpy(&ua, &a, 4); __builtin_memcpy(&ub, &b, 4);
  ua += 0x8000u; ub += 0x8000u;
#if __has_builtin(__builtin_amdgcn_perm)
  return __builtin_amdgcn_perm(ub, ua, 0x07060302u);  // bytes: ua[3:2] | ub[3:2]
#else
  return (ua >> 16) | (ub & 0xFFFF0000u);
#endif
}

static __device__ __forceinline__ s8b pack8(float a0, float a1, float a2, float a3,
                                            float a4, float a5, float a6, float a7) {
  union { unsigned u[4]; s8b v; } x;
  x.u[0] = pack2bf(a0, a1); x.u[1] = pack2bf(a2, a3);
  x.u[2] = pack2bf(a4, a5); x.u[3] = pack2bf(a6, a7);
  return x.v;
}

static __device__ __forceinline__ f32x4 mfma16(s8b a, s8b b, f32x4 c) {
  return __builtin_amdgcn_mfma_f32_16x16x32_bf16(a, b, c, 0, 0, 0);
}
static __device__ __forceinline__ f32x16 mfma32(s8b a, s8b b, f32x16 c) {
  return __builtin_amdgcn_mfma_f32_32x32x16_bf16(a, b, c, 0, 0, 0);
}

// async 16B global->LDS DMA; dest = wave-uniform base + lane*16
static __device__ __forceinline__ void async16(const void* g, void* l) {
  __builtin_amdgcn_global_load_lds(
      (const __attribute__((address_space(1))) void*)g,
      (__attribute__((address_space(3))) void*)l, 16, 0, 0);
}

// ---------------- GroupNorm pass 1: per-(b,g,chunk) partial sum/sumsq ----------------
__global__ void gn_stats(const float* __restrict__ x, float* __restrict__ part) {
  int bx = blockIdx.x;            // 256 = bg(32) * chunk(8)
  int ch = bx & 7, bg = bx >> 3;
  const float* base = x + (size_t)bg * GROUP_ELEMS + (size_t)ch * 8192;
  int t = threadIdx.x;
  float s = 0.f, ss = 0.f;
  #pragma unroll
  for (int i = 0; i < 8; ++i) {
    float4 v = *(const float4*)(base + i * 1024 + t * 4);
    s  += v.x + v.y + v.z + v.w;
    ss += v.x * v.x + v.y * v.y + v.z * v.z + v.w * v.w;
  }
  #pragma unroll
  for (int off = 1; off < 64; off <<= 1) {
    s  += __shfl_xor(s, off);
    ss += __shfl_xor(ss, off);
  }
  __shared__ float red[8];
  int w = t >> 6;
  if ((t & 63) == 0) { red[w * 2] = s; red[w * 2 + 1] = ss; }
  __syncthreads();
  if (t == 0) {
    part[bx * 2]     = red[0] + red[2] + red[4] + red[6];
    part[bx * 2 + 1] = red[1] + red[3] + red[5] + red[7];
  }
}

// ---------------- GroupNorm pass 2: reduce partials, normalize, write xn (b,n,c) bf16 ----------------
__global__ void gn_apply(const float* __restrict__ x, const float* __restrict__ gw,
                         const float* __restrict__ gb, const float* __restrict__ part,
                         short* __restrict__ xn) {
  int bx = blockIdx.x;            // 256 = b(4) g(8) ns(8)
  int ns = bx & 7, g = (bx >> 3) & 7, b = bx >> 6;
  int bg = b * NGRP + g;
  float s = 0.f, ss = 0.f;
  #pragma unroll
  for (int j = 0; j < 8; ++j) {
    s  += part[(bg * 8 + j) * 2];
    ss += part[(bg * 8 + j) * 2 + 1];
  }
  float mean = s * (1.f / GROUP_ELEMS);
  float var  = ss * (1.f / GROUP_ELEMS) - mean * mean;
  float inv  = rsqrtf(var + EPS_GN);
  int t = threadIdx.x;
  int cl = t & 15, n4 = t >> 4;
  int c = g * 16 + cl;
  float ga = gw[c] * inv;
  float be = gb[c] - mean * ga;
  const float* xr = x + (size_t)(b * CCH + c) * NSP;
  short* xo = xn + (size_t)b * NSP * CCH + c;
  #pragma unroll
  for (int i = 0; i < 8; ++i) {
    int n = ns * 512 + i * 64 + n4 * 4;
    float4 v = *(const float4*)(xr + n);
    xo[(size_t)(n + 0) * CCH] = f2bf(v.x * ga + be);
    xo[(size_t)(n + 1) * CCH] = f2bf(v.y * ga + be);
    xo[(size_t)(n + 2) * CCH] = f2bf(v.z * ga + be);
    xo[(size_t)(n + 3) * CCH] = f2bf(v.w * ga + be);
  }
}

// ---------------- Fused QKV: bx<1024 -> q,k (D[n][o]); else -> v (D[o][n], permuted key order) ----------------
// v is written TRANSPOSED (b,c,n); within each 16-key chunk the key order is
// permuted so flash's PV can consume P DIRECTLY from the S^T MFMA C-registers:
// orig key kk (0..15) -> pos = 8*((kk>>2)&1) + (kk&3) + 4*(kk>>3)
__global__ void qkv_gemm(const short* __restrict__ xn, const float* __restrict__ Wqkv,
                         const float* __restrict__ bias, short* __restrict__ q,
                         short* __restrict__ k, short* __restrict__ vt) {
  __shared__ short Xl[128 * 136];
  __shared__ short Wl[64 * 136];
  int bx = blockIdx.x;
  int t = threadIdx.x;
  int lane = t & 63, w = t >> 6, l15 = lane & 15, quad = lane >> 4;
  if (bx < 1024) {
    // ---------- q,k part ----------
    int ot = bx & 3, nt = (bx >> 2) & 63, b = bx >> 8;
    for (int idx = t; idx < 64 * 16; idx += 256) {
      int row = idx >> 4, c8 = idx & 15;
      *(s8b*)&Xl[row * 136 + c8 * 8] =
          *(const s8b*)(xn + ((size_t)(b * NSP + nt * 64 + row)) * CCH + c8 * 8);
    }
    for (int idx = t; idx < 64 * 16; idx += 256) {
      int row = idx >> 4, c8 = idx & 15;
      const float* src = Wqkv + (size_t)(ot * 64 + row) * CCH + c8 * 8;
      s8b wv;
      #pragma unroll
      for (int j = 0; j < 8; ++j) wv[j] = f2bf(src[j]);
      *(s8b*)&Wl[row * 136 + c8 * 8] = wv;
    }
    __syncthreads();
    s8b a[4];
    #pragma unroll
    for (int kc = 0; kc < 4; ++kc)
      a[kc] = *(const s8b*)&Xl[(w * 16 + l15) * 136 + kc * 32 + quad * 8];
    #pragma unroll
    for (int o4 = 0; o4 < 4; ++o4) {
      f32x4 acc = {0.f, 0.f, 0.f, 0.f};
      #pragma unroll
      for (int kc = 0; kc < 4; ++kc) {
        s8b bw = *(const s8b*)&Wl[(o4 * 16 + l15) * 136 + kc * 32 + quad * 8];
        acc = mfma16(a[kc], bw, acc);
      }
      int obase = ot * 64 + o4 * 16;
      short* dst = (obase < 128) ? q : k;
      float mulf = (obase < 128) ? QSCALE : 1.0f;
      int oc = obase - ((obase < 128) ? 0 : 128) + l15;
      float bs = bias[obase + l15];
      #pragma unroll
      for (int r = 0; r < 4; ++r) {
        int n = nt * 64 + w * 16 + quad * 4 + r;
        dst[((size_t)(b * NSP + n)) * CCH + oc] = f2bf((acc[r] + bs) * mulf);
      }
    }
  } else {
    // ---------- v part ----------
    int vbx = bx - 1024;            // 256 = b(4) nt(32) ot(2)
    int ot = vbx & 1, nt = (vbx >> 1) & 31, b = vbx >> 6;
    for (int idx = t; idx < 128 * 16; idx += 256) {
      int row = idx >> 4, c8 = idx & 15;
      *(s8b*)&Xl[row * 136 + c8 * 8] =
          *(const s8b*)(xn + ((size_t)(b * NSP + nt * 128 + row)) * CCH + c8 * 8);
    }
    for (int idx = t; idx < 64 * 16; idx += 256) {
      int row = idx >> 4, c8 = idx & 15;
      const float* src = Wqkv + (size_t)(256 + ot * 64 + row) * CCH + c8 * 8;
      s8b wv;
      #pragma unroll
      for (int j = 0; j < 8; ++j) wv[j] = f2bf(src[j]);
      *(s8b*)&Wl[row * 136 + c8 * 8] = wv;
    }
    __syncthreads();
    s8b a[4];
    #pragma unroll
    for (int kc = 0; kc < 4; ++kc)
      a[kc] = *(const s8b*)&Wl[(w * 16 + l15) * 136 + kc * 32 + quad * 8];
    float bs[4];
    #pragma unroll
    for (int r = 0; r < 4; ++r) bs[r] = bias[256 + ot * 64 + w * 16 + quad * 4 + r];
    // permuted position within the 16-key chunk (see header comment)
    int ppos = 8 * ((l15 >> 2) & 1) + (l15 & 3) + 4 * (l15 >> 3);
    #pragma unroll
    for (int ntile = 0; ntile < 8; ++ntile) {
      f32x4 acc = {0.f, 0.f, 0.f, 0.f};
      #pragma unroll
      for (int kc = 0; kc < 4; ++kc) {
        s8b bx2 = *(const s8b*)&Xl[(ntile * 16 + l15) * 136 + kc * 32 + quad * 8];
        acc = mfma16(a[kc], bx2, acc);
      }
      int npos = nt * 128 + ntile * 16 + ppos;
      #pragma unroll
      for (int r = 0; r < 4; ++r) {
        int og = ot * 64 + w * 16 + quad * 4 + r;     // v channel
        vt[((size_t)(b * CCH + og)) * NSP + npos] = f2bf(acc[r] + bs[r]);
      }
    }
  }
}

// ---------------- Flash attention v8: 32x32 MFMA, register-direct P, no P-LDS ----------------
// Grid 512 = qt(32: 128-row tiles) x b(4) x kh(4 key quarters); 2 blocks/CU.
// Block 256 thr = 4 waves x 32 q-rows. Computes S^T = K Q^T (A=K, B=Q) so the
// C-layout (col=q-row, row=key) is directly a legal B-operand for
// O^T = V^T P^T after exp2+pack — V's in-chunk key permutation (done at
// qkv_gemm) makes the C-reg key order match the B k-slot order. No P LDS.
// l = per-lane scalar sum (a lane's whole C column is ONE q-row) + shfl(32).
// K/V double-buffered via global_load_lds, XOR source swizzle.
__global__ __launch_bounds__(256, 2) void flash(const short* __restrict__ q,
                                                const short* __restrict__ k,
                                                const short* __restrict__ vt,
                                                short* __restrict__ Op,
                                                float* __restrict__ Lp) {
  int bx = blockIdx.x;
  int kh = bx & 3, b = (bx >> 2) & 3, qt = bx >> 4;
  __shared__ short Kl[2][64 * 128];   // [key][ch], 8-short groups XOR-swizzled by (key&15)
  __shared__ short Vl[2][128 * 64];   // [ch][pos], 8-short groups XOR-swizzled by (ch&7)
  int t = threadIdx.x;
  int lane = t & 63, w = t >> 6;
  int l31 = lane & 31, h = lane >> 5;
  const short* kbase = k + (size_t)b * NSP * CCH;
  const short* vbase = vt + (size_t)b * CCH * NSP;
  int kt0 = kh * 1024;

  int krow_in_chunk = lane >> 4, kgrp = lane & 15;
  int vrow_in_chunk = lane >> 3, vgrp = lane & 7;

  // Q B-fragments, resident: qrow = qt*128 + w*32 + l31, c = h*8 + 16*kc
  s8b aq[8];
  {
    const short* qp = q + ((size_t)(b * NSP + qt * 128 + w * 32 + l31)) * CCH + h * 8;
    #pragma unroll
    for (int kc = 0; kc < 8; ++kc) aq[kc] = *(const s8b*)(qp + kc * 16);
  }
  f32x16 O[4];
  #pragma unroll
  for (int cg = 0; cg < 4; ++cg)
    #pragma unroll
    for (int r = 0; r < 16; ++r) O[cg][r] = 0.f;
  float lsum = 0.f;

  #define STAGE(buf_, key0_)                                                        \
    {                                                                               \
      const int key0v = (key0_);                                                    \
      _Pragma("unroll") for (int si = 0; si < 4; ++si) {                            \
        int c = w * 4 + si;                                                         \
        int rt = c * 4 + krow_in_chunk;                                             \
        async16(kbase + (size_t)(key0v + rt) * CCH + ((kgrp ^ (rt & 15)) * 8),      \
                &Kl[buf_][c * 512]);                                                \
        int rc = c * 8 + vrow_in_chunk;                                             \
        async16(vbase + (size_t)rc * NSP + key0v + ((vgrp ^ (rc & 7)) * 8),         \
                &Vl[buf_][c * 512]);                                                \
      }                                                                             \
    }

  STAGE(0, kt0)
  __syncthreads();

  for (int i = 0; i < 16; ++i) {
    int buf = i & 1;
    if (i < 15) STAGE(buf ^ 1, kt0 + (i + 1) * 64)

    s8b pb[4];
    #pragma unroll
    for (int tile = 0; tile < 2; ++tile) {
      // ---- S^T = K Q^T over one 32-key tile ----
      f32x16 st;
      #pragma unroll
      for (int r = 0; r < 16; ++r) st[r] = 0.f;
      const short* kp = &Kl[buf][(tile * 32 + l31) * 128];
      #pragma unroll
      for (int kc = 0; kc < 8; ++kc) {
        s8b ak = *(const s8b*)&kp[(((kc * 2 + h) ^ (l31 & 15))) * 8];
        st = mfma32(ak, aq[kc], st);
      }
      // ---- p = exp2(s); l accumulate; pack C-regs straight into B-operands ----
      float pp[16];
      #pragma unroll
      for (int r = 0; r < 16; ++r) pp[r] = fexp2(st[r]);
      lsum += (((pp[0] + pp[1]) + (pp[2] + pp[3])) + ((pp[4] + pp[5]) + (pp[6] + pp[7]))) +
              (((pp[8] + pp[9]) + (pp[10] + pp[11])) + ((pp[12] + pp[13]) + (pp[14] + pp[15])));
      pb[tile * 2 + 0] = pack8(pp[0], pp[1], pp[2], pp[3], pp[4], pp[5], pp[6], pp[7]);
      pb[tile * 2 + 1] = pack8(pp[8], pp[9], pp[10], pp[11], pp[12], pp[13], pp[14], pp[15]);
    }
    // ---- O^T += V^T P^T ----
    #pragma unroll
    for (int cg = 0; cg < 4; ++cg) {
      const short* vp = &Vl[buf][(cg * 32 + l31) * 64];
      #pragma unroll
      for (int kc2 = 0; kc2 < 4; ++kc2) {
        s8b av = *(const s8b*)&vp[(((kc2 * 2 + h) ^ (l31 & 7))) * 8];
        O[cg] = mfma32(av, pb[kc2], O[cg]);
      }
    }
    __syncthreads();
  }

  // ---- l: combine the two half-lanes sharing a q-row ----
  lsum += __shfl_xor(lsum, 32);

  // ---- epilogue: O^T -> LDS transpose (reuse Kl) -> coalesced global ----
  short* eb = &Kl[0][0] + w * 4096;   // 32 rows x 128 ch bf16, groups swizzled by (n&7)
  #pragma unroll
  for (int cg = 0; cg < 4; ++cg)
    #pragma unroll
    for (int rp = 0; rp < 8; ++rp) {
      int r = rp * 2;
      int chlo = (r & 3) + 4 * h;          // within-8 offset (even)
      int chhi = cg * 4 + (r >> 2);        // 8-short group index
      *(unsigned*)&eb[l31 * 128 + ((chhi ^ (l31 & 7))) * 8 + chlo] =
          pack2bf(O[cg][r], O[cg][r + 1]);
    }
  short* ob = Op + (size_t)kh * OPSTRIDE + ((size_t)(b * NSP + qt * 128)) * CCH;
  float* lp = Lp + kh * LPSTRIDE + b * NSP + qt * 128;
  if (lane < 32) lp[w * 32 + l31] = lsum;
  __syncthreads();
  for (int idx = t; idx < 128 * 16; idx += 256) {
    int row = idx >> 4, c8 = idx & 15;
    int w2 = row >> 5, nl = row & 31;
    *(s8b*)(ob + (size_t)row * CCH + c8 * 8) =
        *(const s8b*)(&Kl[0][0] + w2 * 4096 + nl * 128 + ((c8 ^ (nl & 7))) * 8);
  }
}

// ---------------- proj + bias + residual, merging the 4 kh partials ----------------
__global__ void proj_gemm(const short* __restrict__ Op, const float* __restrict__ Lp,
                          const float* __restrict__ Wp, const float* __restrict__ pbias,
                          const float* __restrict__ x, float* __restrict__ out) {
  int bx = blockIdx.x;            // 256 = b(4) nt(64)
  int nt = bx & 63, b = bx >> 6;
  __shared__ short Wl[128][136];
  int t = threadIdx.x;
  for (int idx = t; idx < 128 * 16; idx += 256) {
    int row = idx >> 4, c8 = idx & 15;
    const float* src = Wp + (size_t)row * CCH + c8 * 8;
    s8b wv;
    #pragma unroll
    for (int j = 0; j < 8; ++j) wv[j] = f2bf(src[j]);
    *(s8b*)&Wl[row][c8 * 8] = wv;
  }
  __syncthreads();
  int lane = t & 63, w = t >> 6, l15 = lane & 15, quad = lane >> 4;
  int row = nt * 64 + w * 16 + l15;             // this lane's ao row (m index)
  float lsum = Lp[0 * LPSTRIDE + b * NSP + row] + Lp[1 * LPSTRIDE + b * NSP + row] +
               Lp[2 * LPSTRIDE + b * NSP + row] + Lp[3 * LPSTRIDE + b * NSP + row];
  float linv = 1.f / lsum;
  const short* ap = Op + ((size_t)(b * NSP + row)) * CCH + quad * 8;
  s8b bfr[4];
  #pragma unroll
  for (int kc = 0; kc < 4; ++kc) {
    float acc8[8];
    #pragma unroll
    for (int j = 0; j < 8; ++j) acc8[j] = 0.f;
    #pragma unroll
    for (int s = 0; s < 4; ++s) {
      s8b tv = *(const s8b*)(ap + (size_t)s * OPSTRIDE + kc * 32);
      #pragma unroll
      for (int j = 0; j < 8; ++j) acc8[j] += bf2f(tv[j]);
    }
    #pragma unroll
    for (int j = 0; j < 8; ++j) bfr[kc][j] = f2bf(acc8[j] * linv);
  }
  #pragma unroll
  for (int cg = 0; cg < 8; ++cg) {
    f32x4 acc = {0.f, 0.f, 0.f, 0.f};
    #pragma unroll
    for (int kc = 0; kc < 4; ++kc) {
      s8b aw = *(const s8b*)&Wl[cg * 16 + l15][kc * 32 + quad * 8];
      acc = mfma16(aw, bfr[kc], acc);
    }
    #pragma unroll
    for (int r = 0; r < 4; ++r) {
      int co = cg * 16 + quad * 4 + r;
      int n = nt * 64 + w * 16 + l15;
      size_t off = ((size_t)(b * CCH + co)) * NSP + n;
      out[off] = x[off] + acc[r] + pbias[co];
    }
  }
}

extern "C" void kernel_launch(void* const* d_in, const int* in_sizes, int n_in,
                              void* d_out, int out_size, void* d_ws, size_t ws_size,
                              hipStream_t stream) {
  (void)in_sizes; (void)n_in; (void)out_size; (void)ws_size;
  const float* x    = (const float*)d_in[0];
  const float* gw   = (const float*)d_in[1];
  const float* gb   = (const float*)d_in[2];
  const float* Wqkv = (const float*)d_in[3];
  const float* bqkv = (const float*)d_in[4];
  const float* Wp   = (const float*)d_in[5];
  const float* bp   = (const float*)d_in[6];
  float* out = (float*)d_out;
  char* ws = (char*)d_ws;
  float* part = (float*)ws;                             // 512 floats
  short* xn    = (short*)(ws + 4096);
  short* q     = (short*)(ws + 4096 + 1ull * 4194304);
  short* k     = (short*)(ws + 4096 + 2ull * 4194304);
  short* vt    = (short*)(ws + 4096 + 3ull * 4194304);
  short* Opart = (short*)(ws + 4096 + 4ull * 4194304);  // 4 x 4MB bf16 partial O
  float* Lpart = (float*)(ws + 4096 + 8ull * 4194304);  // 4 x 64KB fp32 partial l

  gn_stats<<<256, 256, 0, stream>>>(x, part);
  gn_apply<<<256, 256, 0, stream>>>(x, gw, gb, part, xn);
  qkv_gemm<<<1280, 256, 0, stream>>>(xn, Wqkv, bqkv, q, k, vt);
  flash<<<512, 256, 0, stream>>>(q, k, vt, Opart, Lpart);
  proj_gemm<<<256, 256, 0, stream>>>(Opart, Lpart, Wp, bp, x, out);
}